// Round 20
// baseline (286.466 us; speedup 1.0000x reference)
//
#include <hip/hip_runtime.h>

#define NN 10000
#define NE 160000
#define NBK0 157           // ceil(10000/64)
#define NBK1 469           // ceil(30000/64)

constexpr float INV_AVG = 1.0f / 16.0f;
constexpr float INV_SQRT3F = 0.5773502691896258f;

typedef __attribute__((ext_vector_type(8))) short short8v;
typedef __attribute__((ext_vector_type(8))) unsigned short ushort8v;
typedef __attribute__((ext_vector_type(4))) float float4v;

// bf16 pack offsets (ushort units) inside wpk
#define OF_UP0 0
#define OF_UP1 16384
#define OF_SK0 32768
#define OF_SK1 196608
#define OF_LN0 360448
#define OF_LN1 393216
#define WPK_TOT 425984     // 2*16384 + 2*163840 + 2*32768
#define WTP_TOT 49152      // 12 k8-slots x 512 cols x 8 (K padded 80->96)

__device__ __forceinline__ unsigned short f2bf(float f) {
    unsigned int u = __float_as_uint(f);
    return (unsigned short)((u + 0x7FFFu + ((u >> 16) & 1u)) >> 16);
}
__device__ __forceinline__ float bf2f(unsigned short h) {
    return __uint_as_float(((unsigned int)h) << 16);
}

// ---------------------------------------------------------------------------
// Prep: pack W_up0/1 (128x128), W_sk0/1 (1280x128, K a-major: k'=a*128+u),
// W_lin0/1 (256x128) to bf16 [k8][n][8].
// ---------------------------------------------------------------------------
__global__ __launch_bounds__(256) void prep_w_kernel(
    const float* __restrict__ W_up0, const float* __restrict__ W_up1,
    const float* __restrict__ W_sk0, const float* __restrict__ W_sk1,
    const float* __restrict__ W_lin0, const float* __restrict__ W_lin1,
    unsigned short* __restrict__ wpk)
{
    const int g = blockIdx.x * 256 + threadIdx.x;
    if (g >= WPK_TOT / 8) return;
    const float* src; int local, base; bool sk = false;
    if (g < 2048)       { src = W_up0;  local = g;         base = OF_UP0; }
    else if (g < 4096)  { src = W_up1;  local = g - 2048;  base = OF_UP1; }
    else if (g < 24576) { src = W_sk0;  local = g - 4096;  base = OF_SK0; sk = true; }
    else if (g < 45056) { src = W_sk1;  local = g - 24576; base = OF_SK1; sk = true; }
    else if (g < 49152) { src = W_lin0; local = g - 45056; base = OF_LN0; }
    else                { src = W_lin1; local = g - 49152; base = OF_LN1; }
    const int k8 = local >> 7, n = local & 127;
    ushort8v v;
    #pragma unroll
    for (int j = 0; j < 8; ++j) {
        const int k = k8 * 8 + j;
        int row;
        if (sk) { const int a = k >> 7, u = k & 127; row = u * 10 + a; }
        else    { row = k; }
        v[j] = f2bf(src[(size_t)row * 128 + n]);
    }
    *(ushort8v*)(wpk + (size_t)base + (size_t)local * 8) = v;
}

// Pack W_tpw (80x512) to bf16 [k8(12)][col(512)][8], zero-padded k>=80.
__global__ __launch_bounds__(256) void prep_wt_kernel(
    const float* __restrict__ W_tpw, unsigned short* __restrict__ wtp)
{
    const int g = blockIdx.x * 256 + threadIdx.x;
    if (g >= 6144) return;
    const int k8 = g >> 9, col = g & 511;
    ushort8v v;
    #pragma unroll
    for (int j = 0; j < 8; ++j) {
        const int k = k8 * 8 + j;
        v[j] = (k < 80) ? f2bf(W_tpw[(size_t)k * 512 + col]) : (unsigned short)0;
    }
    *(ushort8v*)(wtp + (size_t)g * 8) = v;
}

// ---------------------------------------------------------------------------
// Node stage v2 (unchanged from R17).
// ---------------------------------------------------------------------------
__global__ __launch_bounds__(256, 2) void node_mfma_kernel(
    const float* __restrict__ node_attrs,
    const float* __restrict__ node_feats,
    const unsigned short* __restrict__ wpk,
    float* __restrict__ hbuf,
    float* __restrict__ out)
{
    __shared__ __align__(16) unsigned short habuf[1024][8];    // 16 KB
    __shared__ __align__(16) unsigned short bbuf[2][1024][8];  // 32 KB
    __shared__ float atrow[64][10];                            // 2.5 KB

    const int t = threadIdx.x;
    const int bid = blockIdx.x;
    const bool m1 = (bid >= NBK0);
    const int r0 = m1 ? (bid - NBK0) * 64 : bid * 64;
    const int RTOT = m1 ? 30000 : 10000;

    const unsigned short* __restrict__ wup = wpk + (m1 ? OF_UP1 : OF_UP0);
    const unsigned short* __restrict__ wsk = wpk + (m1 ? OF_SK1 : OF_SK0);

    const int rg_ = t >> 2, pg_ = t & 3;
    const int rr_g = min(r0 + rg_, RTOT - 1);
    int n_g, m_g;
    if (!m1) { n_g = rr_g; m_g = 0; }
    else     { n_g = rr_g / 3; m_g = rr_g - n_g * 3; }
    const int wq = rg_ >> 4, rlq = rg_ & 15;

    #pragma unroll
    for (int q = 0; q < 4; ++q) {
        const int sl = pg_ * 4 + q, ss = sl >> 2, kb = sl & 3;
        const int k0 = ss * 32 + kb * 8;
        ushort8v v;
        if (!m1) {
            const float4 xa_ = *(const float4*)(node_feats + (size_t)n_g * 512 + k0);
            const float4 xb_ = *(const float4*)(node_feats + (size_t)n_g * 512 + k0 + 4);
            v[0] = f2bf(xa_.x); v[1] = f2bf(xa_.y); v[2] = f2bf(xa_.z); v[3] = f2bf(xa_.w);
            v[4] = f2bf(xb_.x); v[5] = f2bf(xb_.y); v[6] = f2bf(xb_.z); v[7] = f2bf(xb_.w);
        } else {
            #pragma unroll
            for (int j = 0; j < 8; ++j)
                v[j] = f2bf(node_feats[(size_t)n_g * 512 + 128 + (k0 + j) * 3 + m_g]);
        }
        *(ushort8v*)&habuf[((ss * 4 + wq) * 4 + kb) * 16 + rlq][0] = v;
    }
    for (int i = t; i < 640; i += 256) {
        const int r = i / 10, a = i - r * 10;
        const int rr = min(r0 + r, RTOT - 1);
        const int n = m1 ? (rr / 3) : rr;
        atrow[r][a] = node_attrs[n * 10 + a];
    }
    __syncthreads();

    const int w = t >> 6, lane = t & 63;
    const int rl = lane & 15, kq = lane >> 4;

    // ---- H phase ----
    {
        float4v hacc[8];
        #pragma unroll
        for (int nt = 0; nt < 8; ++nt) hacc[nt] = (float4v){0.f, 0.f, 0.f, 0.f};

        #pragma unroll
        for (int ss = 0; ss < 4; ++ss) {
            const short8v af = *(const short8v*)&habuf[((ss * 4 + w) * 4 + kq) * 16 + rl][0];
            #pragma unroll
            for (int nt = 0; nt < 8; ++nt) {
                const short8v bf = *(const short8v*)(wup +
                    ((size_t)((ss * 4 + kq) * 128 + nt * 16 + rl)) * 8);
                hacc[nt] = __builtin_amdgcn_mfma_f32_16x16x32_bf16(af, bf, hacc[nt], 0, 0, 0);
            }
        }
        #pragma unroll
        for (int nt = 0; nt < 8; ++nt)
            #pragma unroll
            for (int v2 = 0; v2 < 4; ++v2) {
                const int rr = r0 + w * 16 + kq * 4 + v2;
                if (rr < RTOT) {
                    const int col = nt * 16 + rl;
                    if (!m1) hbuf[(size_t)rr * 512 + col] = hacc[nt][v2];
                    else {
                        const int n = rr / 3, m = rr - n * 3;
                        hbuf[(size_t)n * 512 + 128 + m * 128 + col] = hacc[nt][v2];
                    }
                }
            }
    }

    // ---- SC phase: K=1280 a-major, 20 steps, 1 barrier/step ----
    float4v sacc[8];
    #pragma unroll
    for (int nt = 0; nt < 8; ++nt) sacc[nt] = (float4v){0.f, 0.f, 0.f, 0.f};

    #pragma unroll
    for (int i = 0; i < 4; ++i) {
        const int s = i * 256 + t;
        const int ssb = s >> 9, ntb = (s >> 6) & 7, kbb = (s >> 4) & 3, nlb = s & 15;
        const int k8 = ssb * 4 + kbb;
        const int n = ntb * 16 + nlb;
        *(ushort8v*)&bbuf[0][s][0] =
            *(const ushort8v*)(wsk + ((size_t)(k8 * 128 + n)) * 8);
    }
    __syncthreads();

    int cur = 0;
    for (int ks = 0; ks < 20; ++ks) {
        ushort8v tmp[4];
        if (ks < 19) {
            #pragma unroll
            for (int i = 0; i < 4; ++i) {
                const int s = i * 256 + t;
                const int ssb = s >> 9, ntb = (s >> 6) & 7, kbb = (s >> 4) & 3, nlb = s & 15;
                const int k8 = (ks + 1) * 8 + ssb * 4 + kbb;
                const int n = ntb * 16 + nlb;
                tmp[i] = *(const ushort8v*)(wsk + ((size_t)(k8 * 128 + n)) * 8);
            }
        }

        short8v af[2];
        #pragma unroll
        for (int ss = 0; ss < 2; ++ss) {
            const int kp = ks * 64 + ss * 32 + kq * 8;
            const int a = kp >> 7, u0 = kp & 127;
            const ushort8v xh = *(const ushort8v*)&habuf[
                (((u0 >> 5) * 4 + w) * 4 + ((u0 >> 3) & 3)) * 16 + rl][0];
            const float av = atrow[w * 16 + rl][a];
            ushort8v vv;
            #pragma unroll
            for (int j = 0; j < 8; ++j) vv[j] = f2bf(bf2f(xh[j]) * av);
            af[ss] = (short8v)vv;
        }

        #pragma unroll
        for (int ss = 0; ss < 2; ++ss)
            #pragma unroll
            for (int nt = 0; nt < 8; ++nt) {
                const short8v bf =
                    *(const short8v*)&bbuf[cur][((ss * 8 + nt) * 4 + kq) * 16 + rl][0];
                sacc[nt] = __builtin_amdgcn_mfma_f32_16x16x32_bf16(af[ss], bf, sacc[nt], 0, 0, 0);
            }

        if (ks < 19) {
            #pragma unroll
            for (int i = 0; i < 4; ++i) {
                const int s = i * 256 + t;
                *(ushort8v*)&bbuf[cur ^ 1][s][0] = tmp[i];
            }
        }
        __syncthreads();
        cur ^= 1;
    }

    #pragma unroll
    for (int nt = 0; nt < 8; ++nt)
        #pragma unroll
        for (int v2 = 0; v2 < 4; ++v2) {
            const int rr = r0 + w * 16 + kq * 4 + v2;
            if (rr < RTOT) {
                const int col = nt * 16 + rl;
                if (!m1) out[(size_t)rr * 512 + col] = sacc[nt][v2];
                else {
                    const int n = rr / 3, m = rr - n * 3;
                    out[(size_t)n * 512 + 128 + col * 3 + m] = sacc[nt][v2];
                }
            }
        }
}

// ---------------------------------------------------------------------------
// CSR build (unchanged).
// ---------------------------------------------------------------------------
__global__ __launch_bounds__(256) void hist_kernel(
    const int* __restrict__ recv, int* __restrict__ cnt)
{
    const int e = blockIdx.x * 256 + threadIdx.x;
    if (e < NE) atomicAdd(&cnt[recv[e]], 1);
}

__global__ __launch_bounds__(256) void scan_kernel(
    const int* __restrict__ cnt, int* __restrict__ row_start,
    int* __restrict__ head)
{
    __shared__ int part[256];
    const int t = threadIdx.x;
    const int base = t * 40;
    int s = 0;
    if (base < NN)
        for (int b = 0; b < 40; ++b) s += cnt[base + b];
    part[t] = s;
    __syncthreads();
    const int local = s;
    for (int off = 1; off < 256; off <<= 1) {
        const int v = (t >= off) ? part[t - off] : 0;
        __syncthreads();
        part[t] += v;
        __syncthreads();
    }
    const int excl = part[t] - local;
    if (base < NN) {
        int run = excl;
        for (int b = 0; b < 40; ++b) {
            row_start[base + b] = run;
            head[base + b] = run;
            run += cnt[base + b];
        }
    }
    if (t == 0) row_start[NN] = NE;
}

__global__ __launch_bounds__(256) void scatter_kernel(
    const int* __restrict__ recv, int* __restrict__ head,
    int* __restrict__ elist)
{
    const int e = blockIdx.x * 256 + threadIdx.x;
    if (e < NE) {
        const int p = atomicAdd(&head[recv[e]], 1);
        elist[p] = e;
    }
}

// ---------------------------------------------------------------------------
// Pack v2 (unchanged).
// ---------------------------------------------------------------------------
__global__ __launch_bounds__(256) void pack2_kernel(
    const float* __restrict__ node_attrs,
    const float* __restrict__ edge_attrs,
    const float* __restrict__ edge_feats,
    const int*  __restrict__ edge_index,
    const int*  __restrict__ elist,
    unsigned short* __restrict__ zpk,
    float* __restrict__ ypk)
{
    const int pos = blockIdx.x * 256 + threadIdx.x;
    if (pos >= NE) return;
    const int e = elist[pos];
    const int snd = edge_index[e];

    float ef[8];
    *(float4*)&ef[0] = *(const float4*)(edge_feats + (size_t)e * 8);
    *(float4*)&ef[4] = *(const float4*)(edge_feats + (size_t)e * 8 + 4);
    float at[10];
    #pragma unroll
    for (int a = 0; a < 10; ++a) at[a] = node_attrs[(size_t)snd * 10 + a];

    #pragma unroll
    for (int k8 = 0; k8 < 12; ++k8) {
        ushort8v v;
        #pragma unroll
        for (int j = 0; j < 8; ++j) {
            const int A = k8 * 8 + j;
            const float z = (A < 80) ? at[A >> 3] * ef[A & 7] : 0.f;
            v[j] = f2bf(z);
        }
        *(ushort8v*)(zpk + ((size_t)k8 * NE + pos) * 8) = v;
    }

    const float4 ea = *(const float4*)(edge_attrs + (size_t)e * 4);
    *(float4*)(ypk + (size_t)pos * 8) = ea;
    *(float4*)(ypk + (size_t)pos * 8 + 4) =
        make_float4(__int_as_float(snd), 0.f, 0.f, 0.f);
}

// ---------------------------------------------------------------------------
// Gather v14: BARRIER-FREE. zpk is stored in MFMA-fragment order, so each
// wave loads its A-fragments directly from global (4x256B segments/wave) —
// no LDS, no __syncthreads. Waves free-run over their node list; masked
// lanes (e>=cl) load zero A-frags => zero contributions. snd loaded early
// (h prefetch batched, R13 discipline); y float4 loaded after MFMAs so the
// af registers are dead by then (peak live ~115 < 128 budget).
// ---------------------------------------------------------------------------
__global__ __launch_bounds__(256, 2) void gather_mfma_kernel(
    const unsigned short* __restrict__ wtp,
    const float* __restrict__ hbuf,
    const int*  __restrict__ row_start,
    const unsigned short* __restrict__ zpk,
    const float* __restrict__ ypk,
    float* __restrict__ msgbuf)
{
    const int t = threadIdx.x;
    const int p = blockIdx.x & 1;
    const int ngrp = blockIdx.x >> 1;
    const int w = t >> 6, lane = t & 63;
    const int rl = lane & 15, kq = lane >> 4;

    // B frags: [wi][ks][ct]
    short8v breg[2][3][2];
    #pragma unroll
    for (int wi = 0; wi < 2; ++wi)
        #pragma unroll
        for (int ks = 0; ks < 3; ++ks)
            #pragma unroll
            for (int ct = 0; ct < 2; ++ct) {
                const int col = p * 256 + wi * 128 + w * 32 + ct * 16 + rl;
                breg[wi][ks][ct] = *(const short8v*)(wtp +
                    ((size_t)((ks * 4 + kq) * 512 + col)) * 8);
            }

    for (int nn = 0; nn < 4; ++nn) {
        const int node = ngrp * 4 + nn;
        const int rowst = row_start[node];
        const int deg = row_start[node + 1] - rowst;

        float nacc[2][4];
        #pragma unroll
        for (int ct = 0; ct < 2; ++ct)
            #pragma unroll
            for (int j = 0; j < 4; ++j) nacc[ct][j] = 0.f;

        for (int ce = 0; ce < deg; ce += 32) {
            const int cl = min(32, deg - ce);

            #pragma unroll
            for (int rt = 0; rt < 2; ++rt) {
                if (rt == 1 && cl <= 16) continue;   // zero half: contributes 0

                // ---- snd loads (broadcast across the 16 rl lanes) ----
                int snd[4];
                #pragma unroll
                for (int v = 0; v < 4; ++v) {
                    const int e = rt * 16 + kq * 4 + v;
                    snd[v] = (e < cl)
                        ? __float_as_int(ypk[(size_t)(rowst + ce + e) * 8 + 4]) : 0;
                }

                // ---- batched h prefetch (R13 discipline) ----
                float h0v[4][2];                 // p==0
                float hA[4][2], hB[4][2], hC[4][2]; // p==1
                if (p == 0) {
                    #pragma unroll
                    for (int v = 0; v < 4; ++v) {
                        const float* hrow = hbuf + (size_t)snd[v] * 512;
                        #pragma unroll
                        for (int ct = 0; ct < 2; ++ct)
                            h0v[v][ct] = hrow[w * 32 + ct * 16 + rl];
                    }
                } else {
                    #pragma unroll
                    for (int v = 0; v < 4; ++v) {
                        const float* hrow = hbuf + (size_t)snd[v] * 512;
                        #pragma unroll
                        for (int ct = 0; ct < 2; ++ct) {
                            const int c = w * 32 + ct * 16 + rl;
                            hA[v][ct] = hrow[128 + c];
                            hB[v][ct] = hrow[256 + c];
                            hC[v][ct] = hrow[384 + c];
                        }
                    }
                }

                // ---- A-fragments direct from zpk (fragment-order layout) ----
                short8v af[3];
                {
                    const int e = rt * 16 + rl;
                    #pragma unroll
                    for (int ks = 0; ks < 3; ++ks) {
                        ushort8v vz = {0, 0, 0, 0, 0, 0, 0, 0};
                        if (e < cl)
                            vz = *(const ushort8v*)(zpk +
                                ((size_t)(ks * 4 + kq) * NE + rowst + ce + e) * 8);
                        af[ks] = (short8v)vz;
                    }
                }

                // ---- MFMA ----
                float4v acc[2][2];
                #pragma unroll
                for (int wi = 0; wi < 2; ++wi)
                    #pragma unroll
                    for (int ct = 0; ct < 2; ++ct)
                        acc[wi][ct] = (float4v){0.f, 0.f, 0.f, 0.f};
                #pragma unroll
                for (int ks = 0; ks < 3; ++ks)
                    #pragma unroll
                    for (int wi = 0; wi < 2; ++wi)
                        #pragma unroll
                        for (int ct = 0; ct < 2; ++ct)
                            acc[wi][ct] = __builtin_amdgcn_mfma_f32_16x16x32_bf16(
                                af[ks], breg[wi][ks][ct], acc[wi][ct], 0, 0, 0);

                // ---- y loads (af regs dead now) + epilogue ----
                float4 yv[4];
                #pragma unroll
                for (int v = 0; v < 4; ++v) {
                    const int e = rt * 16 + kq * 4 + v;
                    yv[v] = (e < cl)
                        ? *(const float4*)(ypk + (size_t)(rowst + ce + e) * 8)
                        : make_float4(0.f, 0.f, 0.f, 0.f);
                }

                if (p == 0) {
                    #pragma unroll
                    for (int v = 0; v < 4; ++v) {
                        const float Y0 = yv[v].x, Y10 = yv[v].y;
                        const float Y11 = yv[v].z, Y12 = yv[v].w;
                        #pragma unroll
                        for (int ct = 0; ct < 2; ++ct) {
                            const float tA = acc[0][ct][v];
                            const float tB = acc[1][ct][v];
                            const float h0 = h0v[v][ct];
                            nacc[ct][0] = fmaf(tA * Y0, h0, nacc[ct][0]);
                            const float tm = tB * h0;
                            nacc[ct][1] = fmaf(tm, Y10, nacc[ct][1]);
                            nacc[ct][2] = fmaf(tm, Y11, nacc[ct][2]);
                            nacc[ct][3] = fmaf(tm, Y12, nacc[ct][3]);
                        }
                    }
                } else {
                    #pragma unroll
                    for (int v = 0; v < 4; ++v) {
                        const float Y0 = yv[v].x, Y10 = yv[v].y;
                        const float Y11 = yv[v].z, Y12 = yv[v].w;
                        #pragma unroll
                        for (int ct = 0; ct < 2; ++ct) {
                            const float tA = acc[0][ct][v];
                            const float tB = acc[1][ct][v];
                            const float t2 = tA * Y0;
                            nacc[ct][1] = fmaf(t2, hA[v][ct], nacc[ct][1]);
                            nacc[ct][2] = fmaf(t2, hB[v][ct], nacc[ct][2]);
                            nacc[ct][3] = fmaf(t2, hC[v][ct], nacc[ct][3]);
                            float d = hA[v][ct] * Y10;
                            d = fmaf(hB[v][ct], Y11, d);
                            d = fmaf(hC[v][ct], Y12, d);
                            nacc[ct][0] = fmaf(tB * INV_SQRT3F, d, nacc[ct][0]);
                        }
                    }
                }
            }
        }

        // ---- cross-kq reduce + write ----
        float red[2][4];
        #pragma unroll
        for (int ct = 0; ct < 2; ++ct)
            #pragma unroll
            for (int j = 0; j < 4; ++j) {
                float v = nacc[ct][j];
                v += __shfl_xor(v, 16, 64);
                v += __shfl_xor(v, 32, 64);
                red[ct][j] = v;
            }
        if (kq == 0) {
            float* mrow = msgbuf + (size_t)node * 1024;
            #pragma unroll
            for (int ct = 0; ct < 2; ++ct) {
                const int c = w * 32 + ct * 16 + rl;
                if (p == 0) {
                    mrow[c]       = red[ct][0];
                    mrow[256 + c] = red[ct][1];
                    mrow[512 + c] = red[ct][2];
                    mrow[768 + c] = red[ct][3];
                } else {
                    mrow[128 + c] = red[ct][0];
                    mrow[384 + c] = red[ct][1];
                    mrow[640 + c] = red[ct][2];
                    mrow[896 + c] = red[ct][3];
                }
            }
        }
    }
}

// ---------------------------------------------------------------------------
// Out stage on MFMA (unchanged from R16).
// ---------------------------------------------------------------------------
__global__ __launch_bounds__(256, 2) void out_mfma_kernel(
    const float* __restrict__ msgbuf,
    const unsigned short* __restrict__ wpk,
    float* __restrict__ out)
{
    __shared__ __align__(16) unsigned short habuf[2048][8];   // 32 KB

    const int t = threadIdx.x;
    const int n0 = blockIdx.x * 16;

    const int rg_ = t >> 2, pg_ = t & 3;
    const int wq = rg_ >> 4, rlq = rg_ & 15;
    const float* src = msgbuf + (size_t)(n0 + rlq) * 1024 + wq * 256;

    #pragma unroll
    for (int q = 0; q < 8; ++q) {
        const int sl = pg_ * 8 + q, ss = sl >> 2, kb = sl & 3;
        const int k0 = ss * 32 + kb * 8;
        const float4 xa = *(const float4*)(src + k0);
        const float4 xb = *(const float4*)(src + k0 + 4);
        ushort8v v;
        v[0] = f2bf(xa.x); v[1] = f2bf(xa.y); v[2] = f2bf(xa.z); v[3] = f2bf(xa.w);
        v[4] = f2bf(xb.x); v[5] = f2bf(xb.y); v[6] = f2bf(xb.z); v[7] = f2bf(xb.w);
        *(ushort8v*)&habuf[((ss * 4 + wq) * 4 + kb) * 16 + rlq][0] = v;
    }
    __syncthreads();

    const int w = t >> 6, lane = t & 63;
    const int rl = lane & 15, kq = lane >> 4;
    const unsigned short* __restrict__ wl = wpk + ((w == 0) ? OF_LN0 : OF_LN1);

    float4v acc[8];
    #pragma unroll
    for (int nt = 0; nt < 8; ++nt) acc[nt] = (float4v){0.f, 0.f, 0.f, 0.f};

    #pragma unroll
    for (int ss = 0; ss < 8; ++ss) {
        const short8v af = *(const short8v*)&habuf[((ss * 4 + w) * 4 + kq) * 16 + rl][0];
        #pragma unroll
        for (int nt = 0; nt < 8; ++nt) {
            const short8v bf = *(const short8v*)(wl +
                ((size_t)((ss * 4 + kq) * 128 + nt * 16 + rl)) * 8);
            acc[nt] = __builtin_amdgcn_mfma_f32_16x16x32_bf16(af, bf, acc[nt], 0, 0, 0);
        }
    }

    #pragma unroll
    for (int nt = 0; nt < 8; ++nt)
        #pragma unroll
        for (int v2 = 0; v2 < 4; ++v2) {
            const int n = n0 + kq * 4 + v2;
            const int col = nt * 16 + rl;
            if (w == 0) {
                out[(size_t)n * 512 + col] += acc[nt][v2] * INV_AVG;
            } else {
                const int m = w - 1;
                out[(size_t)n * 512 + 128 + col * 3 + m] += acc[nt][v2] * INV_AVG;
            }
        }
}

extern "C" void kernel_launch(void* const* d_in, const int* in_sizes, int n_in,
                              void* d_out, int out_size, void* d_ws, size_t ws_size,
                              hipStream_t stream) {
    const float* node_attrs = (const float*)d_in[0];
    const float* node_feats = (const float*)d_in[1];
    const float* edge_attrs = (const float*)d_in[2];
    const float* edge_feats = (const float*)d_in[3];
    const int*   edge_index = (const int*)d_in[4];
    const float* W_up0  = (const float*)d_in[5];
    const float* W_up1  = (const float*)d_in[6];
    const float* W_tpw  = (const float*)d_in[7];
    const float* W_lin0 = (const float*)d_in[8];
    const float* W_lin1 = (const float*)d_in[9];
    const float* W_sk0  = (const float*)d_in[10];
    const float* W_sk1  = (const float*)d_in[11];
    float* out = (float*)d_out;

    float* hbuf   = (float*)d_ws;                     // NN*512 f32  (20.5 MB)
    float* msgbuf = hbuf + (size_t)NN * 512;          // NN*1024 f32 (41 MB)
    float* ypk    = msgbuf + (size_t)NN * 1024;       // NE*8 f32    (5.1 MB)
    unsigned short* zpk = (unsigned short*)(ypk + (size_t)NE * 8); // 12*NE*8 bf16 (30.7 MB)
    unsigned short* wpk = zpk + (size_t)12 * NE * 8;
    unsigned short* wtp = wpk + WPK_TOT;
    int* cnt       = (int*)(wtp + WTP_TOT);
    int* row_start = cnt + NN;                        // NN+1
    int* head      = row_start + NN + 1;
    int* elist     = head + NN;                       // NE

    const int* recv = edge_index + NE;

    hipMemsetAsync(cnt, 0, NN * sizeof(int), stream);
    hist_kernel<<<(NE + 255) / 256, 256, 0, stream>>>(recv, cnt);
    scan_kernel<<<1, 256, 0, stream>>>(cnt, row_start, head);
    scatter_kernel<<<(NE + 255) / 256, 256, 0, stream>>>(recv, head, elist);
    pack2_kernel<<<(NE + 255) / 256, 256, 0, stream>>>(
        node_attrs, edge_attrs, edge_feats, edge_index, elist, zpk, ypk);
    prep_w_kernel<<<(WPK_TOT / 8 + 255) / 256, 256, 0, stream>>>(
        W_up0, W_up1, W_sk0, W_sk1, W_lin0, W_lin1, wpk);
    prep_wt_kernel<<<24, 256, 0, stream>>>(W_tpw, wtp);

    node_mfma_kernel<<<NBK0 + NBK1, 256, 0, stream>>>(node_attrs, node_feats,
                                                      wpk, hbuf, out);
    gather_mfma_kernel<<<5000, 256, 0, stream>>>(wtp, hbuf, row_start,
                                                 zpk, ypk, msgbuf);
    out_mfma_kernel<<<NN / 16, 256, 0, stream>>>(msgbuf, wpk, out);
}

// Round 21
// 207.707 us; speedup vs baseline: 1.3792x; 1.3792x over previous
//
#include <hip/hip_runtime.h>

#define NN 10000
#define NE 160000
#define NBK0 157           // ceil(10000/64)
#define NBK1 469           // ceil(30000/64)

constexpr float INV_AVG = 1.0f / 16.0f;
constexpr float INV_SQRT3F = 0.5773502691896258f;

typedef __attribute__((ext_vector_type(8))) short short8v;
typedef __attribute__((ext_vector_type(8))) unsigned short ushort8v;
typedef __attribute__((ext_vector_type(4))) float float4v;

// bf16 pack offsets (ushort units) inside wpk
#define OF_UP0 0
#define OF_UP1 16384
#define OF_SK0 32768
#define OF_SK1 196608
#define OF_LN0 360448
#define OF_LN1 393216
#define WPK_TOT 425984     // 2*16384 + 2*163840 + 2*32768
#define WTP_TOT 49152      // 12 k8-slots x 512 cols x 8 (K padded 80->96)

__device__ __forceinline__ unsigned short f2bf(float f) {
    unsigned int u = __float_as_uint(f);
    return (unsigned short)((u + 0x7FFFu + ((u >> 16) & 1u)) >> 16);
}
__device__ __forceinline__ float bf2f(unsigned short h) {
    return __uint_as_float(((unsigned int)h) << 16);
}

// ---------------------------------------------------------------------------
// Prep: pack W_up0/1 (128x128), W_sk0/1 (1280x128, K a-major: k'=a*128+u),
// W_lin0/1 (256x128) to bf16 [k8][n][8].
// ---------------------------------------------------------------------------
__global__ __launch_bounds__(256) void prep_w_kernel(
    const float* __restrict__ W_up0, const float* __restrict__ W_up1,
    const float* __restrict__ W_sk0, const float* __restrict__ W_sk1,
    const float* __restrict__ W_lin0, const float* __restrict__ W_lin1,
    unsigned short* __restrict__ wpk)
{
    const int g = blockIdx.x * 256 + threadIdx.x;
    if (g >= WPK_TOT / 8) return;
    const float* src; int local, base; bool sk = false;
    if (g < 2048)       { src = W_up0;  local = g;         base = OF_UP0; }
    else if (g < 4096)  { src = W_up1;  local = g - 2048;  base = OF_UP1; }
    else if (g < 24576) { src = W_sk0;  local = g - 4096;  base = OF_SK0; sk = true; }
    else if (g < 45056) { src = W_sk1;  local = g - 24576; base = OF_SK1; sk = true; }
    else if (g < 49152) { src = W_lin0; local = g - 45056; base = OF_LN0; }
    else                { src = W_lin1; local = g - 49152; base = OF_LN1; }
    const int k8 = local >> 7, n = local & 127;
    ushort8v v;
    #pragma unroll
    for (int j = 0; j < 8; ++j) {
        const int k = k8 * 8 + j;
        int row;
        if (sk) { const int a = k >> 7, u = k & 127; row = u * 10 + a; }
        else    { row = k; }
        v[j] = f2bf(src[(size_t)row * 128 + n]);
    }
    *(ushort8v*)(wpk + (size_t)base + (size_t)local * 8) = v;
}

// Pack W_tpw (80x512) to bf16 [k8(12)][col(512)][8], zero-padded k>=80.
__global__ __launch_bounds__(256) void prep_wt_kernel(
    const float* __restrict__ W_tpw, unsigned short* __restrict__ wtp)
{
    const int g = blockIdx.x * 256 + threadIdx.x;
    if (g >= 6144) return;
    const int k8 = g >> 9, col = g & 511;
    ushort8v v;
    #pragma unroll
    for (int j = 0; j < 8; ++j) {
        const int k = k8 * 8 + j;
        v[j] = (k < 80) ? f2bf(W_tpw[(size_t)k * 512 + col]) : (unsigned short)0;
    }
    *(ushort8v*)(wtp + (size_t)g * 8) = v;
}

// ---------------------------------------------------------------------------
// Node stage v2 (unchanged from R17).
// ---------------------------------------------------------------------------
__global__ __launch_bounds__(256, 2) void node_mfma_kernel(
    const float* __restrict__ node_attrs,
    const float* __restrict__ node_feats,
    const unsigned short* __restrict__ wpk,
    float* __restrict__ hbuf,
    float* __restrict__ out)
{
    __shared__ __align__(16) unsigned short habuf[1024][8];    // 16 KB
    __shared__ __align__(16) unsigned short bbuf[2][1024][8];  // 32 KB
    __shared__ float atrow[64][10];                            // 2.5 KB

    const int t = threadIdx.x;
    const int bid = blockIdx.x;
    const bool m1 = (bid >= NBK0);
    const int r0 = m1 ? (bid - NBK0) * 64 : bid * 64;
    const int RTOT = m1 ? 30000 : 10000;

    const unsigned short* __restrict__ wup = wpk + (m1 ? OF_UP1 : OF_UP0);
    const unsigned short* __restrict__ wsk = wpk + (m1 ? OF_SK1 : OF_SK0);

    const int rg_ = t >> 2, pg_ = t & 3;
    const int rr_g = min(r0 + rg_, RTOT - 1);
    int n_g, m_g;
    if (!m1) { n_g = rr_g; m_g = 0; }
    else     { n_g = rr_g / 3; m_g = rr_g - n_g * 3; }
    const int wq = rg_ >> 4, rlq = rg_ & 15;

    #pragma unroll
    for (int q = 0; q < 4; ++q) {
        const int sl = pg_ * 4 + q, ss = sl >> 2, kb = sl & 3;
        const int k0 = ss * 32 + kb * 8;
        ushort8v v;
        if (!m1) {
            const float4 xa_ = *(const float4*)(node_feats + (size_t)n_g * 512 + k0);
            const float4 xb_ = *(const float4*)(node_feats + (size_t)n_g * 512 + k0 + 4);
            v[0] = f2bf(xa_.x); v[1] = f2bf(xa_.y); v[2] = f2bf(xa_.z); v[3] = f2bf(xa_.w);
            v[4] = f2bf(xb_.x); v[5] = f2bf(xb_.y); v[6] = f2bf(xb_.z); v[7] = f2bf(xb_.w);
        } else {
            #pragma unroll
            for (int j = 0; j < 8; ++j)
                v[j] = f2bf(node_feats[(size_t)n_g * 512 + 128 + (k0 + j) * 3 + m_g]);
        }
        *(ushort8v*)&habuf[((ss * 4 + wq) * 4 + kb) * 16 + rlq][0] = v;
    }
    for (int i = t; i < 640; i += 256) {
        const int r = i / 10, a = i - r * 10;
        const int rr = min(r0 + r, RTOT - 1);
        const int n = m1 ? (rr / 3) : rr;
        atrow[r][a] = node_attrs[n * 10 + a];
    }
    __syncthreads();

    const int w = t >> 6, lane = t & 63;
    const int rl = lane & 15, kq = lane >> 4;

    // ---- H phase ----
    {
        float4v hacc[8];
        #pragma unroll
        for (int nt = 0; nt < 8; ++nt) hacc[nt] = (float4v){0.f, 0.f, 0.f, 0.f};

        #pragma unroll
        for (int ss = 0; ss < 4; ++ss) {
            const short8v af = *(const short8v*)&habuf[((ss * 4 + w) * 4 + kq) * 16 + rl][0];
            #pragma unroll
            for (int nt = 0; nt < 8; ++nt) {
                const short8v bf = *(const short8v*)(wup +
                    ((size_t)((ss * 4 + kq) * 128 + nt * 16 + rl)) * 8);
                hacc[nt] = __builtin_amdgcn_mfma_f32_16x16x32_bf16(af, bf, hacc[nt], 0, 0, 0);
            }
        }
        #pragma unroll
        for (int nt = 0; nt < 8; ++nt)
            #pragma unroll
            for (int v2 = 0; v2 < 4; ++v2) {
                const int rr = r0 + w * 16 + kq * 4 + v2;
                if (rr < RTOT) {
                    const int col = nt * 16 + rl;
                    if (!m1) hbuf[(size_t)rr * 512 + col] = hacc[nt][v2];
                    else {
                        const int n = rr / 3, m = rr - n * 3;
                        hbuf[(size_t)n * 512 + 128 + m * 128 + col] = hacc[nt][v2];
                    }
                }
            }
    }

    // ---- SC phase: K=1280 a-major, 20 steps, 1 barrier/step ----
    float4v sacc[8];
    #pragma unroll
    for (int nt = 0; nt < 8; ++nt) sacc[nt] = (float4v){0.f, 0.f, 0.f, 0.f};

    #pragma unroll
    for (int i = 0; i < 4; ++i) {
        const int s = i * 256 + t;
        const int ssb = s >> 9, ntb = (s >> 6) & 7, kbb = (s >> 4) & 3, nlb = s & 15;
        const int k8 = ssb * 4 + kbb;
        const int n = ntb * 16 + nlb;
        *(ushort8v*)&bbuf[0][s][0] =
            *(const ushort8v*)(wsk + ((size_t)(k8 * 128 + n)) * 8);
    }
    __syncthreads();

    int cur = 0;
    for (int ks = 0; ks < 20; ++ks) {
        ushort8v tmp[4];
        if (ks < 19) {
            #pragma unroll
            for (int i = 0; i < 4; ++i) {
                const int s = i * 256 + t;
                const int ssb = s >> 9, ntb = (s >> 6) & 7, kbb = (s >> 4) & 3, nlb = s & 15;
                const int k8 = (ks + 1) * 8 + ssb * 4 + kbb;
                const int n = ntb * 16 + nlb;
                tmp[i] = *(const ushort8v*)(wsk + ((size_t)(k8 * 128 + n)) * 8);
            }
        }

        short8v af[2];
        #pragma unroll
        for (int ss = 0; ss < 2; ++ss) {
            const int kp = ks * 64 + ss * 32 + kq * 8;
            const int a = kp >> 7, u0 = kp & 127;
            const ushort8v xh = *(const ushort8v*)&habuf[
                (((u0 >> 5) * 4 + w) * 4 + ((u0 >> 3) & 3)) * 16 + rl][0];
            const float av = atrow[w * 16 + rl][a];
            ushort8v vv;
            #pragma unroll
            for (int j = 0; j < 8; ++j) vv[j] = f2bf(bf2f(xh[j]) * av);
            af[ss] = (short8v)vv;
        }

        #pragma unroll
        for (int ss = 0; ss < 2; ++ss)
            #pragma unroll
            for (int nt = 0; nt < 8; ++nt) {
                const short8v bf =
                    *(const short8v*)&bbuf[cur][((ss * 8 + nt) * 4 + kq) * 16 + rl][0];
                sacc[nt] = __builtin_amdgcn_mfma_f32_16x16x32_bf16(af[ss], bf, sacc[nt], 0, 0, 0);
            }

        if (ks < 19) {
            #pragma unroll
            for (int i = 0; i < 4; ++i) {
                const int s = i * 256 + t;
                *(ushort8v*)&bbuf[cur ^ 1][s][0] = tmp[i];
            }
        }
        __syncthreads();
        cur ^= 1;
    }

    #pragma unroll
    for (int nt = 0; nt < 8; ++nt)
        #pragma unroll
        for (int v2 = 0; v2 < 4; ++v2) {
            const int rr = r0 + w * 16 + kq * 4 + v2;
            if (rr < RTOT) {
                const int col = nt * 16 + rl;
                if (!m1) out[(size_t)rr * 512 + col] = sacc[nt][v2];
                else {
                    const int n = rr / 3, m = rr - n * 3;
                    out[(size_t)n * 512 + 128 + col * 3 + m] = sacc[nt][v2];
                }
            }
        }
}

// ---------------------------------------------------------------------------
// CSR build (unchanged).
// ---------------------------------------------------------------------------
__global__ __launch_bounds__(256) void hist_kernel(
    const int* __restrict__ recv, int* __restrict__ cnt)
{
    const int e = blockIdx.x * 256 + threadIdx.x;
    if (e < NE) atomicAdd(&cnt[recv[e]], 1);
}

__global__ __launch_bounds__(256) void scan_kernel(
    const int* __restrict__ cnt, int* __restrict__ row_start,
    int* __restrict__ head)
{
    __shared__ int part[256];
    const int t = threadIdx.x;
    const int base = t * 40;
    int s = 0;
    if (base < NN)
        for (int b = 0; b < 40; ++b) s += cnt[base + b];
    part[t] = s;
    __syncthreads();
    const int local = s;
    for (int off = 1; off < 256; off <<= 1) {
        const int v = (t >= off) ? part[t - off] : 0;
        __syncthreads();
        part[t] += v;
        __syncthreads();
    }
    const int excl = part[t] - local;
    if (base < NN) {
        int run = excl;
        for (int b = 0; b < 40; ++b) {
            row_start[base + b] = run;
            head[base + b] = run;
            run += cnt[base + b];
        }
    }
    if (t == 0) row_start[NN] = NE;
}

__global__ __launch_bounds__(256) void scatter_kernel(
    const int* __restrict__ recv, int* __restrict__ head,
    int* __restrict__ elist)
{
    const int e = blockIdx.x * 256 + threadIdx.x;
    if (e < NE) {
        const int p = atomicAdd(&head[recv[e]], 1);
        elist[p] = e;
    }
}

// ---------------------------------------------------------------------------
// Pack v2 (unchanged).
// ---------------------------------------------------------------------------
__global__ __launch_bounds__(256) void pack2_kernel(
    const float* __restrict__ node_attrs,
    const float* __restrict__ edge_attrs,
    const float* __restrict__ edge_feats,
    const int*  __restrict__ edge_index,
    const int*  __restrict__ elist,
    unsigned short* __restrict__ zpk,
    float* __restrict__ ypk)
{
    const int pos = blockIdx.x * 256 + threadIdx.x;
    if (pos >= NE) return;
    const int e = elist[pos];
    const int snd = edge_index[e];

    float ef[8];
    *(float4*)&ef[0] = *(const float4*)(edge_feats + (size_t)e * 8);
    *(float4*)&ef[4] = *(const float4*)(edge_feats + (size_t)e * 8 + 4);
    float at[10];
    #pragma unroll
    for (int a = 0; a < 10; ++a) at[a] = node_attrs[(size_t)snd * 10 + a];

    #pragma unroll
    for (int k8 = 0; k8 < 12; ++k8) {
        ushort8v v;
        #pragma unroll
        for (int j = 0; j < 8; ++j) {
            const int A = k8 * 8 + j;
            const float z = (A < 80) ? at[A >> 3] * ef[A & 7] : 0.f;
            v[j] = f2bf(z);
        }
        *(ushort8v*)(zpk + ((size_t)k8 * NE + pos) * 8) = v;
    }

    const float4 ea = *(const float4*)(edge_attrs + (size_t)e * 4);
    *(float4*)(ypk + (size_t)pos * 8) = ea;
    *(float4*)(ypk + (size_t)pos * 8 + 4) =
        make_float4(__int_as_float(snd), 0.f, 0.f, 0.f);
}

// ---------------------------------------------------------------------------
// Gather v11 (R17-proven best: 2-barrier chunk loop, LDS staging, rt-skip,
// (256,2)). R18 pipeline / R19 p-merge / R20 barrier-free all regressed —
// this structure is the measured floor (~88 us).
// ---------------------------------------------------------------------------
__global__ __launch_bounds__(256, 2) void gather_mfma_kernel(
    const unsigned short* __restrict__ wtp,
    const float* __restrict__ hbuf,
    const int*  __restrict__ row_start,
    const unsigned short* __restrict__ zpk,
    const float* __restrict__ ypk,
    float* __restrict__ msgbuf)
{
    __shared__ __align__(16) unsigned short zb[384][8];   // 6 KB
    __shared__ float yb[32][9];                           // 1.2 KB

    const int t = threadIdx.x;
    const int p = blockIdx.x & 1;
    const int ngrp = blockIdx.x >> 1;
    const int w = t >> 6, lane = t & 63;
    const int rl = lane & 15, kq = lane >> 4;

    // B frags: [wi][ks][ct]
    short8v breg[2][3][2];
    #pragma unroll
    for (int wi = 0; wi < 2; ++wi)
        #pragma unroll
        for (int ks = 0; ks < 3; ++ks)
            #pragma unroll
            for (int ct = 0; ct < 2; ++ct) {
                const int col = p * 256 + wi * 128 + w * 32 + ct * 16 + rl;
                breg[wi][ks][ct] = *(const short8v*)(wtp +
                    ((size_t)((ks * 4 + kq) * 512 + col)) * 8);
            }

    for (int nn = 0; nn < 4; ++nn) {
        const int node = ngrp * 4 + nn;
        const int rowst = row_start[node];
        const int deg = row_start[node + 1] - rowst;

        float nacc[2][4];
        #pragma unroll
        for (int ct = 0; ct < 2; ++ct)
            #pragma unroll
            for (int j = 0; j < 4; ++j) nacc[ct][j] = 0.f;

        for (int ce = 0; ce < deg; ce += 32) {
            const int cl = min(32, deg - ce);
            __syncthreads();   // protect previous chunk's LDS reads

            // ---- stage zb (coalesced 16B) ----
            {
                const int s = t;
                const int rl2 = s & 15, kq2 = (s >> 4) & 3;
                const int rowt2 = (s >> 6) & 1, ks2 = s >> 7;
                const int e = rowt2 * 16 + rl2;
                const int k8 = ks2 * 4 + kq2;
                ushort8v v = {0, 0, 0, 0, 0, 0, 0, 0};
                if (e < cl)
                    v = *(const ushort8v*)(zpk + ((size_t)k8 * NE + rowst + ce + e) * 8);
                *(ushort8v*)&zb[s][0] = v;
            }
            {
                const int s = 256 + t;
                if (s < 384) {
                    const int rl2 = s & 15, kq2 = (s >> 4) & 3;
                    const int rowt2 = (s >> 6) & 1, ks2 = s >> 7;
                    const int e = rowt2 * 16 + rl2;
                    const int k8 = ks2 * 4 + kq2;
                    ushort8v v = {0, 0, 0, 0, 0, 0, 0, 0};
                    if (e < cl)
                        v = *(const ushort8v*)(zpk + ((size_t)k8 * NE + rowst + ce + e) * 8);
                    *(ushort8v*)&zb[s][0] = v;
                }
            }
            // ---- stage yb (stride 9: conflict-free broadcast) ----
            if (t < 64) {
                const int row = t >> 1, half = t & 1;
                float4 v = make_float4(0.f, 0.f, 0.f, 0.f);
                if (row < cl)
                    v = *(const float4*)(ypk + (size_t)(rowst + ce + row) * 8 + half * 4);
                yb[row][half * 4 + 0] = v.x;
                yb[row][half * 4 + 1] = v.y;
                yb[row][half * 4 + 2] = v.z;
                yb[row][half * 4 + 3] = v.w;
            }
            __syncthreads();

            if (p == 0) {
                #pragma unroll
                for (int rt = 0; rt < 2; ++rt) {
                    if (rt == 1 && cl <= 16) continue;  // zero half: contributes 0
                    float h0v[4][2];
                    #pragma unroll
                    for (int v = 0; v < 4; ++v) {
                        const int e = rt * 16 + kq * 4 + v;
                        const int snd = __float_as_int(yb[e][4]);
                        const float* hrow = hbuf + (size_t)snd * 512;
                        #pragma unroll
                        for (int ct = 0; ct < 2; ++ct)
                            h0v[v][ct] = hrow[w * 32 + ct * 16 + rl];
                    }
                    float4v acc[2][2];
                    #pragma unroll
                    for (int wi = 0; wi < 2; ++wi)
                        #pragma unroll
                        for (int ct = 0; ct < 2; ++ct)
                            acc[wi][ct] = (float4v){0.f, 0.f, 0.f, 0.f};
                    #pragma unroll
                    for (int ks = 0; ks < 3; ++ks) {
                        const short8v af =
                            *(const short8v*)&zb[ks * 128 + rt * 64 + lane][0];
                        #pragma unroll
                        for (int wi = 0; wi < 2; ++wi)
                            #pragma unroll
                            for (int ct = 0; ct < 2; ++ct)
                                acc[wi][ct] = __builtin_amdgcn_mfma_f32_16x16x32_bf16(
                                    af, breg[wi][ks][ct], acc[wi][ct], 0, 0, 0);
                    }
                    #pragma unroll
                    for (int v = 0; v < 4; ++v) {
                        const int e = rt * 16 + kq * 4 + v;
                        const float Y0  = yb[e][0];
                        const float Y10 = yb[e][1];
                        const float Y11 = yb[e][2];
                        const float Y12 = yb[e][3];
                        #pragma unroll
                        for (int ct = 0; ct < 2; ++ct) {
                            const float tA = acc[0][ct][v];
                            const float tB = acc[1][ct][v];
                            const float h0 = h0v[v][ct];
                            nacc[ct][0] = fmaf(tA * Y0, h0, nacc[ct][0]);
                            const float tm = tB * h0;
                            nacc[ct][1] = fmaf(tm, Y10, nacc[ct][1]);
                            nacc[ct][2] = fmaf(tm, Y11, nacc[ct][2]);
                            nacc[ct][3] = fmaf(tm, Y12, nacc[ct][3]);
                        }
                    }
                }
            } else {
                #pragma unroll
                for (int rt = 0; rt < 2; ++rt) {
                    if (rt == 1 && cl <= 16) continue;  // zero half: contributes 0
                    float hA[4][2], hB[4][2], hC[4][2];
                    #pragma unroll
                    for (int v = 0; v < 4; ++v) {
                        const int e = rt * 16 + kq * 4 + v;
                        const int snd = __float_as_int(yb[e][4]);
                        const float* hrow = hbuf + (size_t)snd * 512;
                        #pragma unroll
                        for (int ct = 0; ct < 2; ++ct) {
                            const int c = w * 32 + ct * 16 + rl;
                            hA[v][ct] = hrow[128 + c];
                            hB[v][ct] = hrow[256 + c];
                            hC[v][ct] = hrow[384 + c];
                        }
                    }
                    float4v acc[2][2];
                    #pragma unroll
                    for (int wi = 0; wi < 2; ++wi)
                        #pragma unroll
                        for (int ct = 0; ct < 2; ++ct)
                            acc[wi][ct] = (float4v){0.f, 0.f, 0.f, 0.f};
                    #pragma unroll
                    for (int ks = 0; ks < 3; ++ks) {
                        const short8v af =
                            *(const short8v*)&zb[ks * 128 + rt * 64 + lane][0];
                        #pragma unroll
                        for (int wi = 0; wi < 2; ++wi)
                            #pragma unroll
                            for (int ct = 0; ct < 2; ++ct)
                                acc[wi][ct] = __builtin_amdgcn_mfma_f32_16x16x32_bf16(
                                    af, breg[wi][ks][ct], acc[wi][ct], 0, 0, 0);
                    }
                    #pragma unroll
                    for (int v = 0; v < 4; ++v) {
                        const int e = rt * 16 + kq * 4 + v;
                        const float Y0  = yb[e][0];
                        const float Y10 = yb[e][1];
                        const float Y11 = yb[e][2];
                        const float Y12 = yb[e][3];
                        #pragma unroll
                        for (int ct = 0; ct < 2; ++ct) {
                            const float tA = acc[0][ct][v];
                            const float tB = acc[1][ct][v];
                            const float t2 = tA * Y0;
                            nacc[ct][1] = fmaf(t2, hA[v][ct], nacc[ct][1]);
                            nacc[ct][2] = fmaf(t2, hB[v][ct], nacc[ct][2]);
                            nacc[ct][3] = fmaf(t2, hC[v][ct], nacc[ct][3]);
                            float d = hA[v][ct] * Y10;
                            d = fmaf(hB[v][ct], Y11, d);
                            d = fmaf(hC[v][ct], Y12, d);
                            nacc[ct][0] = fmaf(tB * INV_SQRT3F, d, nacc[ct][0]);
                        }
                    }
                }
            }
        }

        // ---- cross-kq reduce + write ----
        float red[2][4];
        #pragma unroll
        for (int ct = 0; ct < 2; ++ct)
            #pragma unroll
            for (int j = 0; j < 4; ++j) {
                float v = nacc[ct][j];
                v += __shfl_xor(v, 16, 64);
                v += __shfl_xor(v, 32, 64);
                red[ct][j] = v;
            }
        if (kq == 0) {
            float* mrow = msgbuf + (size_t)node * 1024;
            #pragma unroll
            for (int ct = 0; ct < 2; ++ct) {
                const int c = w * 32 + ct * 16 + rl;
                if (p == 0) {
                    mrow[c]       = red[ct][0];
                    mrow[256 + c] = red[ct][1];
                    mrow[512 + c] = red[ct][2];
                    mrow[768 + c] = red[ct][3];
                } else {
                    mrow[128 + c] = red[ct][0];
                    mrow[384 + c] = red[ct][1];
                    mrow[640 + c] = red[ct][2];
                    mrow[896 + c] = red[ct][3];
                }
            }
        }
    }
}

// ---------------------------------------------------------------------------
// Out stage on MFMA (unchanged from R16).
// ---------------------------------------------------------------------------
__global__ __launch_bounds__(256, 2) void out_mfma_kernel(
    const float* __restrict__ msgbuf,
    const unsigned short* __restrict__ wpk,
    float* __restrict__ out)
{
    __shared__ __align__(16) unsigned short habuf[2048][8];   // 32 KB

    const int t = threadIdx.x;
    const int n0 = blockIdx.x * 16;

    const int rg_ = t >> 2, pg_ = t & 3;
    const int wq = rg_ >> 4, rlq = rg_ & 15;
    const float* src = msgbuf + (size_t)(n0 + rlq) * 1024 + wq * 256;

    #pragma unroll
    for (int q = 0; q < 8; ++q) {
        const int sl = pg_ * 8 + q, ss = sl >> 2, kb = sl & 3;
        const int k0 = ss * 32 + kb * 8;
        const float4 xa = *(const float4*)(src + k0);
        const float4 xb = *(const float4*)(src + k0 + 4);
        ushort8v v;
        v[0] = f2bf(xa.x); v[1] = f2bf(xa.y); v[2] = f2bf(xa.z); v[3] = f2bf(xa.w);
        v[4] = f2bf(xb.x); v[5] = f2bf(xb.y); v[6] = f2bf(xb.z); v[7] = f2bf(xb.w);
        *(ushort8v*)&habuf[((ss * 4 + wq) * 4 + kb) * 16 + rlq][0] = v;
    }
    __syncthreads();

    const int w = t >> 6, lane = t & 63;
    const int rl = lane & 15, kq = lane >> 4;
    const unsigned short* __restrict__ wl = wpk + ((w == 0) ? OF_LN0 : OF_LN1);

    float4v acc[8];
    #pragma unroll
    for (int nt = 0; nt < 8; ++nt) acc[nt] = (float4v){0.f, 0.f, 0.f, 0.f};

    #pragma unroll
    for (int ss = 0; ss < 8; ++ss) {
        const short8v af = *(const short8v*)&habuf[((ss * 4 + w) * 4 + kq) * 16 + rl][0];
        #pragma unroll
        for (int nt = 0; nt < 8; ++nt) {
            const short8v bf = *(const short8v*)(wl +
                ((size_t)((ss * 4 + kq) * 128 + nt * 16 + rl)) * 8);
            acc[nt] = __builtin_amdgcn_mfma_f32_16x16x32_bf16(af, bf, acc[nt], 0, 0, 0);
        }
    }

    #pragma unroll
    for (int nt = 0; nt < 8; ++nt)
        #pragma unroll
        for (int v2 = 0; v2 < 4; ++v2) {
            const int n = n0 + kq * 4 + v2;
            const int col = nt * 16 + rl;
            if (w == 0) {
                out[(size_t)n * 512 + col] += acc[nt][v2] * INV_AVG;
            } else {
                const int m = w - 1;
                out[(size_t)n * 512 + 128 + col * 3 + m] += acc[nt][v2] * INV_AVG;
            }
        }
}

extern "C" void kernel_launch(void* const* d_in, const int* in_sizes, int n_in,
                              void* d_out, int out_size, void* d_ws, size_t ws_size,
                              hipStream_t stream) {
    const float* node_attrs = (const float*)d_in[0];
    const float* node_feats = (const float*)d_in[1];
    const float* edge_attrs = (const float*)d_in[2];
    const float* edge_feats = (const float*)d_in[3];
    const int*   edge_index = (const int*)d_in[4];
    const float* W_up0  = (const float*)d_in[5];
    const float* W_up1  = (const float*)d_in[6];
    const float* W_tpw  = (const float*)d_in[7];
    const float* W_lin0 = (const float*)d_in[8];
    const float* W_lin1 = (const float*)d_in[9];
    const float* W_sk0  = (const float*)d_in[10];
    const float* W_sk1  = (const float*)d_in[11];
    float* out = (float*)d_out;

    float* hbuf   = (float*)d_ws;                     // NN*512 f32  (20.5 MB)
    float* msgbuf = hbuf + (size_t)NN * 512;          // NN*1024 f32 (41 MB)
    float* ypk    = msgbuf + (size_t)NN * 1024;       // NE*8 f32    (5.1 MB)
    unsigned short* zpk = (unsigned short*)(ypk + (size_t)NE * 8); // 12*NE*8 bf16 (30.7 MB)
    unsigned short* wpk = zpk + (size_t)12 * NE * 8;
    unsigned short* wtp = wpk + WPK_TOT;
    int* cnt       = (int*)(wtp + WTP_TOT);
    int* row_start = cnt + NN;                        // NN+1
    int* head      = row_start + NN + 1;
    int* elist     = head + NN;                       // NE

    const int* recv = edge_index + NE;

    hipMemsetAsync(cnt, 0, NN * sizeof(int), stream);
    hist_kernel<<<(NE + 255) / 256, 256, 0, stream>>>(recv, cnt);
    scan_kernel<<<1, 256, 0, stream>>>(cnt, row_start, head);
    scatter_kernel<<<(NE + 255) / 256, 256, 0, stream>>>(recv, head, elist);
    pack2_kernel<<<(NE + 255) / 256, 256, 0, stream>>>(
        node_attrs, edge_attrs, edge_feats, edge_index, elist, zpk, ypk);
    prep_w_kernel<<<(WPK_TOT / 8 + 255) / 256, 256, 0, stream>>>(
        W_up0, W_up1, W_sk0, W_sk1, W_lin0, W_lin1, wpk);
    prep_wt_kernel<<<24, 256, 0, stream>>>(W_tpw, wtp);

    node_mfma_kernel<<<NBK0 + NBK1, 256, 0, stream>>>(node_attrs, node_feats,
                                                      wpk, hbuf, out);
    gather_mfma_kernel<<<5000, 256, 0, stream>>>(wtp, hbuf, row_start,
                                                 zpk, ypk, msgbuf);
    out_mfma_kernel<<<NN / 16, 256, 0, stream>>>(msgbuf, wpk, out);
}